// Round 1
// 338.468 us; speedup vs baseline: 1.0832x; 1.0832x over previous
//
#include <hip/hip_runtime.h>

// Problem dims
#define S_ 32
#define T_ 64
#define B_ 64
#define V_ 32000
#define E_ 128
#define H_ 128
#define G_ 128
#define C_ 5

typedef short s8v __attribute__((ext_vector_type(8)));   // 8 bf16 payload
typedef __bf16 b8v __attribute__((ext_vector_type(8)));
typedef float f32x4 __attribute__((ext_vector_type(4)));

// --- MFMA wrapper: tolerate either builtin operand signature (short8 or bf16x8)
template <typename V>
__device__ inline auto mfma_sel(V a, V b, f32x4 c, int)
    -> decltype(__builtin_amdgcn_mfma_f32_16x16x32_bf16(a, b, c, 0, 0, 0)) {
  return __builtin_amdgcn_mfma_f32_16x16x32_bf16(a, b, c, 0, 0, 0);
}
template <typename V>
__device__ inline f32x4 mfma_sel(V a, V b, f32x4 c, long) {
  return __builtin_amdgcn_mfma_f32_16x16x32_bf16(
      __builtin_bit_cast(b8v, a), __builtin_bit_cast(b8v, b), c, 0, 0, 0);
}
__device__ inline f32x4 mfma16(s8v a, s8v b, f32x4 c) { return mfma_sel(a, b, c, 0); }

__device__ inline float b2f(unsigned short u) {
  union { unsigned int i; float f; } v; v.i = ((unsigned int)u) << 16; return v.f;
}
// round-to-nearest (ties away) — 2 instr; RNE tie diff is <=1ulp, irrelevant at 2% tol
__device__ inline unsigned short f2b(float f) {
  union { float f; unsigned int i; } v; v.f = f;
  return (unsigned short)((v.i + 0x8000u) >> 16);
}
// full-RNE for the precomputed tables (cheap there, done once per element)
__device__ inline unsigned short f2b_rne(float f) {
  union { float f; unsigned int i; } v; v.f = f;
  unsigned int r = (v.i + 0x7fffu + ((v.i >> 16) & 1u)) >> 16;
  return (unsigned short)r;
}
__device__ inline s8v cvt8(const float* p) {
  const float4 a = *(const float4*)p;
  const float4 b = *(const float4*)(p + 4);
  s8v r;
  r[0] = (short)f2b_rne(a.x); r[1] = (short)f2b_rne(a.y);
  r[2] = (short)f2b_rne(a.z); r[3] = (short)f2b_rne(a.w);
  r[4] = (short)f2b_rne(b.x); r[5] = (short)f2b_rne(b.y);
  r[6] = (short)f2b_rne(b.z); r[7] = (short)f2b_rne(b.w);
  return r;
}
// division-free activations: raw v_rcp_f32 + v_exp_f32 (1 instr each).
__device__ inline float fsigm(float x) {
  return __builtin_amdgcn_rcpf(1.f + __builtin_amdgcn_exp2f(-1.44269504f * x));
}
__device__ inline float ftanh(float x) {
  return 1.f - 2.f * __builtin_amdgcn_rcpf(1.f + __builtin_amdgcn_exp2f(2.88539008f * x));
}

// LDS-only barrier: waits LDS ops, does NOT drain vmcnt — global loads issued
// before this stay in flight across it (cross-wave data here is LDS-only).
__device__ inline void lds_barrier() {
  asm volatile("s_waitcnt lgkmcnt(0)\n\ts_barrier" ::: "memory");
}

// ============================================================================
// K1: gtab[v][c] = sum_e emb[v][e]*Wih_intra[c][e] + bih[c] (+bhh[c] folded for
// r,z gates). MFMA GEMM. Blocks 3000..3003: coalesced transpose of W_W_intra.
// ============================================================================
__global__ __launch_bounds__(256) void k_gtab(
    const float* __restrict__ emb,
    const float* __restrict__ wih,   // [768][128] fp32
    const float* __restrict__ bih,   // [768] fp32
    const float* __restrict__ bhh,   // [768] fp32 (r,z folded; n NOT)
    const float* __restrict__ wwi,   // [256][256] fp32 (h-major)
    unsigned short* __restrict__ gtab,   // [V][768] bf16
    unsigned short* __restrict__ wta)    // [256][256] bf16 (n-major)
{
  __shared__ __align__(16) unsigned short smem[64 * 264];  // union: alds / tbuf
  const int bid = blockIdx.x, tid = threadIdx.x;
  if (bid >= 3000) {  // LDS-tiled transpose, 4 blocks x 64 n-rows
    const int n0 = (bid - 3000) * 64;
    for (int i = 0; i < 64; ++i) {
      int cid = i * 256 + tid;
      int k = cid >> 6, nl = cid & 63;
      smem[nl * 264 + k] = f2b_rne(wwi[k * 256 + n0 + nl]);  // coalesced read
    }
    __syncthreads();
    for (int i = 0; i < 8; ++i) {
      int cid = i * 256 + tid;
      int nl = cid >> 5, k8 = cid & 31;
      *(int4*)&wta[(size_t)(n0 + nl) * 256 + k8 * 8] =
          *(const int4*)&smem[nl * 264 + k8 * 8];            // coalesced write
    }
    return;
  }
  const int mchunk = bid / 6, nchunk = bid % 6;
  const int vbase = mchunk * 64, nbase = nchunk * 128;
  for (int i = 0; i < 8; ++i) {
    int cid = i * 256 + tid;           // 2048 chunks of 4 floats
    int row = cid >> 5, kc = cid & 31;
    float4 v = *(const float4*)&emb[(size_t)(vbase + row) * 128 + kc * 4];
    ushort4 u;
    u.x = f2b_rne(v.x); u.y = f2b_rne(v.y); u.z = f2b_rne(v.z); u.w = f2b_rne(v.w);
    *(ushort4*)&smem[row * 136 + kc * 4] = u;
  }
  __syncthreads();
  const int w = tid >> 6, l = tid & 63, q = l >> 4, ln = l & 15;
  s8v bf[2][4];
  float bias[2];
  for (int nt = 0; nt < 2; ++nt) {
    int c = nbase + (w * 2 + nt) * 16 + ln;
    int g = (c < 384) ? c : (c - 384);       // gate index within direction
    bias[nt] = bih[c] + (g < 256 ? bhh[c] : 0.f);  // fold r,z recurrent bias
    for (int kf = 0; kf < 4; ++kf)
      bf[nt][kf] = cvt8(&wih[(size_t)c * 128 + kf * 32 + q * 8]);
  }
  for (int mt = 0; mt < 4; ++mt) {
    s8v af[4];
    for (int kf = 0; kf < 4; ++kf)
      af[kf] = *(const s8v*)&smem[(mt * 16 + ln) * 136 + kf * 32 + q * 8];
    for (int nt = 0; nt < 2; ++nt) {
      f32x4 acc = {0.f, 0.f, 0.f, 0.f};
      for (int kf = 0; kf < 4; ++kf) acc = mfma16(af[kf], bf[nt][kf], acc);
      const int col = nbase + (w * 2 + nt) * 16 + ln;
      for (int r = 0; r < 4; ++r) {
        const int row = vbase + mt * 16 + q * 4 + r;
        gtab[(size_t)row * 768 + col] = f2b_rne(acc[r] + bias[nt]);
      }
    }
  }
}

// ============================================================================
// K2: intra biGRU. Grid 256 = (s, dir, b-quad of 16): 16 REAL batches per
// N=16 tile (no duplicated lanes). Double-buffered h in LDS, one LDS-only
// barrier/step, next-step gate gather prefetched into registers.
// ============================================================================
__global__ __launch_bounds__(512) void k_intra(
    const int* __restrict__ tokens,
    const unsigned short* __restrict__ gtab,  // bf16, r/z biases folded
    const float* __restrict__ whh,            // [2][384][128] fp32
    const float* __restrict__ bhh,            // [2][384] fp32 (n-gate used)
    unsigned short* __restrict__ iout)        // [S*T*B][256] bf16 internal
{
  const int bid = blockIdx.x;
  const int s = bid >> 3, dir = (bid >> 2) & 1, bq = bid & 3;
  const int bbase = bq * 16;
  const int tid = threadIdx.x;
  const int w = tid >> 6, l = tid & 63, q = l >> 4, ln = l & 15;
  const int gbase = w * 16, g0 = gbase + q * 4;

  __shared__ __align__(16) unsigned short hb[2][16 * 136];
  __shared__ int tokl[T_ * 16];

  for (int i = tid; i < 2 * 16 * 136; i += 512) ((unsigned short*)hb)[i] = 0;
  for (int i = tid; i < T_ * 16; i += 512) {
    int t = i >> 4, bl = i & 15;
    tokl[i] = tokens[(s * T_ + t) * B_ + bbase + bl];
  }

  s8v af[3][4];
  float hbn[4];
  const float* whd = whh + (size_t)dir * (384 * 128);
  const float* bhd = bhh + dir * 384;
  for (int g3 = 0; g3 < 3; ++g3) {
    const int R = g3 * 128 + gbase;
    for (int kf = 0; kf < 4; ++kf)
      af[g3][kf] = cvt8(&whd[(size_t)(R + ln) * 128 + kf * 32 + q * 8]);
  }
  for (int r = 0; r < 4; ++r) hbn[r] = bhd[256 + gbase + q * 4 + r];  // n-gate only
  float h[4] = {0.f, 0.f, 0.f, 0.f};
  const int b = bbase + ln;
  __syncthreads();

  const int tfirst = dir ? (T_ - 1) : 0;
  const unsigned short* gr0 =
      gtab + (size_t)tokl[tfirst * 16 + ln] * 768 + dir * 384 + g0;
  ushort4 xr = *(const ushort4*)&gr0[0];
  ushort4 xz = *(const ushort4*)&gr0[128];
  ushort4 xn = *(const ushort4*)&gr0[256];

  int p = 0;
  for (int step = 0; step < T_; ++step) {
    const int t = dir ? (T_ - 1 - step) : step;
    const int t1 = dir ? (t > 0 ? t - 1 : 0) : (t < T_ - 1 ? t + 1 : T_ - 1);
    // prefetch next step's gates (stays in flight across the lds barrier)
    const unsigned short* grn =
        gtab + (size_t)tokl[t1 * 16 + ln] * 768 + dir * 384 + g0;
    const ushort4 xrn = *(const ushort4*)&grn[0];
    const ushort4 xzn = *(const ushort4*)&grn[128];
    const ushort4 xnn = *(const ushort4*)&grn[256];

    s8v bfr[4];
    for (int kf = 0; kf < 4; ++kf)
      bfr[kf] = *(const s8v*)&hb[p][ln * 136 + kf * 32 + q * 8];
    f32x4 c0 = {0.f, 0.f, 0.f, 0.f}, c1 = c0, c2 = c0;
    for (int kf = 0; kf < 4; ++kf) {
      c0 = mfma16(af[0][kf], bfr[kf], c0);
      c1 = mfma16(af[1][kf], bfr[kf], c1);
      c2 = mfma16(af[2][kf], bfr[kf], c2);
    }

    const unsigned short* xrp = (const unsigned short*)&xr;
    const unsigned short* xzp = (const unsigned short*)&xz;
    const unsigned short* xnp = (const unsigned short*)&xn;
    unsigned short hnb[4];
    for (int r = 0; r < 4; ++r) {
      float rr = fsigm(b2f(xrp[r]) + c0[r]);                 // bhh_r folded
      float zz = fsigm(b2f(xzp[r]) + c1[r]);                 // bhh_z folded
      float nn = ftanh(b2f(xnp[r]) + rr * (c2[r] + hbn[r])); // bhh_n inside r*()
      float hv = zz * (h[r] - nn) + nn;
      h[r] = hv;
      hnb[r] = f2b(hv);
    }
    ushort4 hv4; hv4.x = hnb[0]; hv4.y = hnb[1]; hv4.z = hnb[2]; hv4.w = hnb[3];
    *(ushort4*)&hb[p ^ 1][ln * 136 + g0] = hv4;
    *(ushort4*)&iout[((size_t)(s * T_ + t) * B_ + b) * 256 + dir * 128 + g0] = hv4;
    lds_barrier();
    p ^= 1;
    xr = xrn; xz = xzn; xn = xnn;
  }
}

// ============================================================================
// K3 (fused attn): one pass over iout. Grid 256 = (s, b-group of 8).
// Full W_W_intra (256x256 bf16 = 128 KB) staged in LDS (gfx950 has 160 KB/CU).
// Per M-tile (2 t x 8 b): GEMM logits -> exp (no max needed: |logit| <=
// sum|proj| ~ 13, fp32-safe) -> weighted accumulate into per-lane O[8][8]
// REUSING the af fragments already in registers (flash-style, single iout
// read). Cross-wave merge: shfl_xor(8) for t-pairs, then deterministic
// tree-add through the (now free) W LDS region.
// ============================================================================
__global__ __launch_bounds__(512, 1) void k_attn(
    const unsigned short* __restrict__ iout,  // bf16 internal
    const unsigned short* __restrict__ wta,   // bf16 [256][256] n-major
    const float* __restrict__ bint,           // [256] fp32
    const float* __restrict__ proj,           // [256] fp32
    float* __restrict__ sv)                   // [S*B][256] fp32
{
  __shared__ __align__(16) unsigned short wlds[256 * 256];  // 128 KB, XOR-swizzled
  __shared__ float lgbuf[8][16];
  __shared__ float lbuf[8][8];
  const int tid = threadIdx.x, bid = blockIdx.x;
  const int s = bid >> 3, b0 = (bid & 7) * 8;
  // stage full W (both halves), same swizzle as before
  for (int i = 0; i < 16; ++i) {
    int cid = i * 512 + tid;          // 8192 16B chunks
    int n = cid >> 5, kc = cid & 31;
    *(int4*)&wlds[n * 256 + ((kc ^ (n & 15)) << 3)] =
        *(const int4*)&wta[(size_t)n * 256 + kc * 8];
  }
  const int w = tid >> 6, l = tid & 63, q = l >> 4, ln = l & 15;
  float bbv[16], ppv[16];
  for (int nt = 0; nt < 16; ++nt) {     // per-lane bias/proj for its n-cols
    bbv[nt] = bint[nt * 16 + ln];
    ppv[nt] = proj[nt * 16 + ln];
  }
  __syncthreads();

  float O[8][8];                        // [kf][j] weighted-sum accumulator
  for (int kf = 0; kf < 8; ++kf)
    for (int j = 0; j < 8; ++j) O[kf][j] = 0.f;
  float l_acc = 0.f;

  for (int tile = 0; tile < 4; ++tile) {  // wave w owns t = 8w .. 8w+7
    const int t = (w * 4 + tile) * 2 + (ln >> 3);
    const size_t row = (size_t)((s * T_ + t) * B_ + b0 + (ln & 7));
    s8v af[8];
    for (int kf = 0; kf < 8; ++kf)
      af[kf] = *(const s8v*)&iout[row * 256 + kf * 32 + q * 8];
    float p0 = 0.f, p1 = 0.f, p2 = 0.f, p3 = 0.f;
    for (int nt = 0; nt < 16; ++nt) {
      f32x4 c = {0.f, 0.f, 0.f, 0.f};
      for (int kf = 0; kf < 8; ++kf) {
        s8v bf = *(const s8v*)&wlds[(nt * 16 + ln) * 256 + (((kf * 4 + q) ^ ln) << 3)];
        c = mfma16(af[kf], bf, c);
      }
      p0 += ppv[nt] * ftanh(c[0] + bbv[nt]);
      p1 += ppv[nt] * ftanh(c[1] + bbv[nt]);
      p2 += ppv[nt] * ftanh(c[2] + bbv[nt]);
      p3 += ppv[nt] * ftanh(c[3] + bbv[nt]);
    }
    for (int d = 1; d < 16; d <<= 1) {   // reduce over n-col lanes
      p0 += __shfl_xor(p0, d); p1 += __shfl_xor(p1, d);
      p2 += __shfl_xor(p2, d); p3 += __shfl_xor(p3, d);
    }
    // remap logits (held per D-row q*4+r) to A-row layout via same-wave LDS
    if (ln == 0) {
      lgbuf[w][q * 4 + 0] = p0; lgbuf[w][q * 4 + 1] = p1;
      lgbuf[w][q * 4 + 2] = p2; lgbuf[w][q * 4 + 3] = p3;
    }
    const float lg = lgbuf[w][ln];       // logit for THIS lane's (t,b) row
    const float e = __builtin_amdgcn_exp2f(1.44269504f * lg);
    l_acc += e;
    for (int kf = 0; kf < 8; ++kf)
      for (int j = 0; j < 8; ++j)
        O[kf][j] += e * b2f((unsigned short)af[kf][j]);
  }
  // merge t-pair lanes (ln, ln+8): same b, same dims
  l_acc += __shfl_xor(l_acc, 8);
  for (int kf = 0; kf < 8; ++kf)
    for (int j = 0; j < 8; ++j) O[kf][j] += __shfl_xor(O[kf][j], 8);
  __syncthreads();                       // everyone done reading wlds
  float* obuf = (float*)wlds;            // overlay: [8 waves][8 b][256 d]
  if (ln < 8) {
    const int base = w * 2048 + ln * 256 + q * 8;
    for (int kf = 0; kf < 8; ++kf) {
      float4 v0; v0.x = O[kf][0]; v0.y = O[kf][1]; v0.z = O[kf][2]; v0.w = O[kf][3];
      float4 v1; v1.x = O[kf][4]; v1.y = O[kf][5]; v1.z = O[kf][6]; v1.w = O[kf][7];
      *(float4*)&obuf[base + kf * 32]     = v0;
      *(float4*)&obuf[base + kf * 32 + 4] = v1;
    }
    if (q == 0) lbuf[w][ln] = l_acc;
  }
  __syncthreads();
  // deterministic 8-way reduce + softmax normalize + store sv
  const int idx = tid * 4;               // 2048 outputs / 512 threads
  const int bb_ = idx >> 8;
  float4 acc; acc.x = 0.f; acc.y = 0.f; acc.z = 0.f; acc.w = 0.f;
  float lsum = 0.f;
  for (int w8 = 0; w8 < 8; ++w8) {
    const float4 v = *(const float4*)&obuf[w8 * 2048 + idx];
    acc.x += v.x; acc.y += v.y; acc.z += v.z; acc.w += v.w;
    lsum += lbuf[w8][bb_];
  }
  const float inv = __builtin_amdgcn_rcpf(lsum);
  float4 r; r.x = acc.x * inv; r.y = acc.y * inv; r.z = acc.z * inv; r.w = acc.w * inv;
  *(float4*)&sv[(size_t)((s * B_ + b0 + bb_) * 256) + (idx & 255)] = r;
}

// ============================================================================
// K4: inter input gates xgi = sv @ Wih_inter^T + bih_inter (+bhh r,z folded)
// ============================================================================
__global__ __launch_bounds__(256) void k_xgi(
    const float* __restrict__ sv,
    const float* __restrict__ wihI,  // [768][256] fp32
    const float* __restrict__ bihI,  // [768] fp32
    const float* __restrict__ bhhI,  // [768] fp32
    float* __restrict__ xgi)         // [2][2048][384]
{
  const int bid = blockIdx.x, tid = threadIdx.x;
  const int r0 = bid * 8;
  __shared__ float svl[8 * 256];
  for (int i = 0; i < 8; ++i) svl[i * 256 + tid] = sv[(size_t)(r0 + i) * 256 + tid];
  __syncthreads();
  for (int cc = 0; cc < 3; ++cc) {
    const int c = cc * 256 + tid;
    const int dir = c / 384, g = c - dir * 384;
    const float bias = bihI[c] + (g < 256 ? bhhI[c] : 0.f);  // fold r,z
    float acc[8];
    for (int i = 0; i < 8; ++i) acc[i] = bias;
    const float* wr = wihI + (size_t)c * 256;
    for (int hh = 0; hh < 256; ++hh) {
      const float wv = wr[hh];
      for (int i = 0; i < 8; ++i) acc[i] += wv * svl[i * 256 + hh];
    }
    for (int i = 0; i < 8; ++i)
      xgi[((size_t)dir * 2048 + r0 + i) * 384 + g] = acc[i];
  }
}

// ============================================================================
// K5: inter biGRU. Grid 8 = (dir, b-quad of 16). Same pipeline as K2.
// ============================================================================
__global__ __launch_bounds__(512) void k_inter(
    const float* __restrict__ xgi,   // r,z biases folded
    const float* __restrict__ whh,   // [2][384][128] fp32
    const float* __restrict__ bhh,   // [2][384] fp32 (n-gate used)
    float* __restrict__ io2)         // [S*B][256] fp32
{
  const int bid = blockIdx.x;
  const int dir = bid >> 2, bq = bid & 3, bbase = bq * 16;
  const int tid = threadIdx.x;
  const int w = tid >> 6, l = tid & 63, q = l >> 4, ln = l & 15;
  const int gbase = w * 16, g0 = gbase + q * 4;
  __shared__ __align__(16) unsigned short hb[2][16 * 136];
  for (int i = tid; i < 2 * 16 * 136; i += 512) ((unsigned short*)hb)[i] = 0;
  s8v af[3][4];
  float hbn[4];
  const float* whd = whh + (size_t)dir * (384 * 128);
  const float* bhd = bhh + dir * 384;
  for (int g3 = 0; g3 < 3; ++g3) {
    const int R = g3 * 128 + gbase;
    for (int kf = 0; kf < 4; ++kf)
      af[g3][kf] = cvt8(&whd[(size_t)(R + ln) * 128 + kf * 32 + q * 8]);
  }
  for (int r = 0; r < 4; ++r) hbn[r] = bhd[256 + gbase + q * 4 + r];
  float h[4] = {0.f, 0.f, 0.f, 0.f};
  const int b = bbase + ln;
  __syncthreads();

  const int sfirst = dir ? (S_ - 1) : 0;
  const float* xp0 = xgi + ((size_t)dir * 2048 + sfirst * 64 + b) * 384 + g0;
  float4 vr = *(const float4*)&xp0[0];
  float4 vz = *(const float4*)&xp0[128];
  float4 vn = *(const float4*)&xp0[256];

  int p = 0;
  for (int step = 0; step < S_; ++step) {
    const int sI = dir ? (S_ - 1 - step) : step;
    const int s1 = dir ? (sI > 0 ? sI - 1 : 0) : (sI < S_ - 1 ? sI + 1 : S_ - 1);
    const float* xpn = xgi + ((size_t)dir * 2048 + s1 * 64 + b) * 384 + g0;
    const float4 vrn = *(const float4*)&xpn[0];
    const float4 vzn = *(const float4*)&xpn[128];
    const float4 vnn = *(const float4*)&xpn[256];

    s8v bfr[4];
    for (int kf = 0; kf < 4; ++kf)
      bfr[kf] = *(const s8v*)&hb[p][ln * 136 + kf * 32 + q * 8];
    f32x4 c0 = {0.f, 0.f, 0.f, 0.f}, c1 = c0, c2 = c0;
    for (int kf = 0; kf < 4; ++kf) {
      c0 = mfma16(af[0][kf], bfr[kf], c0);
      c1 = mfma16(af[1][kf], bfr[kf], c1);
      c2 = mfma16(af[2][kf], bfr[kf], c2);
    }
    const float irv[4] = {vr.x, vr.y, vr.z, vr.w};
    const float izv[4] = {vz.x, vz.y, vz.z, vz.w};
    const float inv[4] = {vn.x, vn.y, vn.z, vn.w};
    unsigned short hnb[4];
    for (int r = 0; r < 4; ++r) {
      float rr = fsigm(irv[r] + c0[r]);
      float zz = fsigm(izv[r] + c1[r]);
      float nn = ftanh(inv[r] + rr * (c2[r] + hbn[r]));
      float hv = zz * (h[r] - nn) + nn;
      h[r] = hv;
      hnb[r] = f2b(hv);
    }
    ushort4 hv4; hv4.x = hnb[0]; hv4.y = hnb[1]; hv4.z = hnb[2]; hv4.w = hnb[3];
    *(ushort4*)&hb[p ^ 1][ln * 136 + g0] = hv4;
    float4 of4; of4.x = h[0]; of4.y = h[1]; of4.z = h[2]; of4.w = h[3];
    *(float4*)&io2[((size_t)(sI * 64 + b)) * 256 + dir * 128 + g0] = of4;
    lds_barrier();
    p ^= 1;
    vr = vrn; vz = vzn; vn = vnn;
  }
}

// ============================================================================
// K6: a2[s*64+b] = proj_inter . tanh(io2 @ W_W_inter + b_inter)  (no softmax)
// ============================================================================
__global__ __launch_bounds__(256) void k_attn_i(
    const float* __restrict__ io2,
    const float* __restrict__ wwI,   // [256][256] fp32 h-major
    const float* __restrict__ bI,
    const float* __restrict__ projI,
    float* __restrict__ a2)          // [2048]
{
  const int bid = blockIdx.x, tid = threadIdx.x;
  const int r0 = bid * 8;
  __shared__ float iol[8 * 256];
  __shared__ float red[4 * 8];
  for (int i = 0; i < 8; ++i) iol[i * 256 + tid] = io2[(size_t)(r0 + i) * 256 + tid];
  __syncthreads();
  float acc[8];
  for (int i = 0; i < 8; ++i) acc[i] = 0.f;
  for (int hh = 0; hh < 256; ++hh) {
    const float wv = wwI[hh * 256 + tid];
    for (int i = 0; i < 8; ++i) acc[i] += wv * iol[i * 256 + hh];
  }
  const float bb = bI[tid], pp = projI[tid];
  float p[8];
  for (int i = 0; i < 8; ++i) p[i] = pp * ftanh(acc[i] + bb);
  for (int d = 1; d < 64; d <<= 1)
    for (int i = 0; i < 8; ++i) p[i] += __shfl_xor(p[i], d);
  const int w = tid >> 6, l = tid & 63;
  if (l == 0)
    for (int i = 0; i < 8; ++i) red[w * 8 + i] = p[i];
  __syncthreads();
  if (tid < 8) a2[r0 + tid] = red[tid] + red[8 + tid] + red[16 + tid] + red[24 + tid];
}

// ============================================================================
// K7: doc_vec = sum_s a2 * io2 ; out = doc @ W_final^T + b_final  (fp32 out)
// ============================================================================
__global__ __launch_bounds__(256) void k_final(
    const float* __restrict__ a2,
    const float* __restrict__ io2,
    const float* __restrict__ wf,    // [5][256] fp32
    const float* __restrict__ bfi,   // [5] fp32
    float* __restrict__ out)         // [64][5] fp32
{
  const int b = blockIdx.x, tid = threadIdx.x;
  __shared__ float av[S_];
  __shared__ float dv[256];
  __shared__ float red[4];
  if (tid < S_) av[tid] = a2[tid * 64 + b];
  __syncthreads();
  float acc = 0.f;
  for (int s = 0; s < S_; ++s) acc += av[s] * io2[((size_t)(s * 64 + b)) * 256 + tid];
  dv[tid] = acc;
  __syncthreads();
  for (int c = 0; c < C_; ++c) {
    float pv = wf[c * 256 + tid] * dv[tid];
    for (int d = 1; d < 64; d <<= 1) pv += __shfl_xor(pv, d);
    const int w = tid >> 6, l = tid & 63;
    if (l == 0) red[w] = pv;
    __syncthreads();
    if (tid == 0)
      out[b * C_ + c] = red[0] + red[1] + red[2] + red[3] + bfi[c];
    __syncthreads();
  }
}

// ============================================================================
extern "C" void kernel_launch(void* const* d_in, const int* in_sizes, int n_in,
                              void* d_out, int out_size, void* d_ws, size_t ws_size,
                              hipStream_t stream) {
  (void)in_sizes; (void)n_in; (void)out_size; (void)ws_size;
  const int*   tokens = (const int*)d_in[0];
  const float* emb    = (const float*)d_in[1];
  const float* wih_a  = (const float*)d_in[2];
  const float* whh_a  = (const float*)d_in[3];
  const float* bih_a  = (const float*)d_in[4];
  const float* bhh_a  = (const float*)d_in[5];
  const float* ww_a   = (const float*)d_in[6];
  const float* b_a    = (const float*)d_in[7];
  const float* proj_a = (const float*)d_in[8];
  const float* wih_i  = (const float*)d_in[9];
  const float* whh_i  = (const float*)d_in[10];
  const float* bih_i  = (const float*)d_in[11];
  const float* bhh_i  = (const float*)d_in[12];
  const float* ww_i   = (const float*)d_in[13];
  const float* b_i    = (const float*)d_in[14];
  const float* proj_i = (const float*)d_in[15];
  const float* w_fin  = (const float*)d_in[16];
  const float* b_fin  = (const float*)d_in[17];

  char* ws = (char*)d_ws;
  unsigned short* gtab = (unsigned short*)(ws + 0);          // 49,152,000 B
  unsigned short* wta  = (unsigned short*)(ws + 49152000);   //    131,072 B
  unsigned short* iout = (unsigned short*)(ws + 49283072);   // 67,108,864 B
  float* sv  = (float*)(ws + 117440512);                     //  2,097,152 B
  float* xgi = (float*)(ws + 119537664);                     //  6,291,456 B
  float* io2 = (float*)(ws + 125829120);                     //  2,097,152 B
  float* a2  = (float*)(ws + 127926272);                     //      8,192 B

  k_gtab<<<3004, 256, 0, stream>>>(emb, wih_a, bih_a, bhh_a, ww_a, gtab, wta);
  k_intra<<<256, 512, 0, stream>>>(tokens, gtab, whh_a, bhh_a, iout);
  k_attn<<<256, 512, 0, stream>>>(iout, wta, b_a, proj_a, sv);
  k_xgi<<<256, 256, 0, stream>>>(sv, wih_i, bih_i, bhh_i, xgi);
  k_inter<<<8, 512, 0, stream>>>(xgi, whh_i, bhh_i, io2);
  k_attn_i<<<256, 256, 0, stream>>>(io2, ww_i, b_i, proj_i, a2);
  k_final<<<64, 256, 0, stream>>>(a2, io2, w_fin, b_fin, (float*)d_out);
}

// Round 2
// 311.812 us; speedup vs baseline: 1.1758x; 1.0855x over previous
//
#include <hip/hip_runtime.h>

// Problem dims
#define S_ 32
#define T_ 64
#define B_ 64
#define V_ 32000
#define E_ 128
#define H_ 128
#define G_ 128
#define C_ 5

typedef short s8v __attribute__((ext_vector_type(8)));   // 8 bf16 payload
typedef __bf16 b8v __attribute__((ext_vector_type(8)));
typedef float f32x4 __attribute__((ext_vector_type(4)));

// --- MFMA wrapper: tolerate either builtin operand signature (short8 or bf16x8)
template <typename V>
__device__ inline auto mfma_sel(V a, V b, f32x4 c, int)
    -> decltype(__builtin_amdgcn_mfma_f32_16x16x32_bf16(a, b, c, 0, 0, 0)) {
  return __builtin_amdgcn_mfma_f32_16x16x32_bf16(a, b, c, 0, 0, 0);
}
template <typename V>
__device__ inline f32x4 mfma_sel(V a, V b, f32x4 c, long) {
  return __builtin_amdgcn_mfma_f32_16x16x32_bf16(
      __builtin_bit_cast(b8v, a), __builtin_bit_cast(b8v, b), c, 0, 0, 0);
}
__device__ inline f32x4 mfma16(s8v a, s8v b, f32x4 c) { return mfma_sel(a, b, c, 0); }

__device__ inline float b2f(unsigned short u) {
  union { unsigned int i; float f; } v; v.i = ((unsigned int)u) << 16; return v.f;
}
// round-to-nearest (ties away) — 2 instr; RNE tie diff is <=1ulp, irrelevant at 2% tol
__device__ inline unsigned short f2b(float f) {
  union { float f; unsigned int i; } v; v.f = f;
  return (unsigned short)((v.i + 0x8000u) >> 16);
}
// full-RNE for the precomputed tables (cheap there, done once per element)
__device__ inline unsigned short f2b_rne(float f) {
  union { float f; unsigned int i; } v; v.f = f;
  unsigned int r = (v.i + 0x7fffu + ((v.i >> 16) & 1u)) >> 16;
  return (unsigned short)r;
}
__device__ inline s8v cvt8(const float* p) {
  const float4 a = *(const float4*)p;
  const float4 b = *(const float4*)(p + 4);
  s8v r;
  r[0] = (short)f2b_rne(a.x); r[1] = (short)f2b_rne(a.y);
  r[2] = (short)f2b_rne(a.z); r[3] = (short)f2b_rne(a.w);
  r[4] = (short)f2b_rne(b.x); r[5] = (short)f2b_rne(b.y);
  r[6] = (short)f2b_rne(b.z); r[7] = (short)f2b_rne(b.w);
  return r;
}
// division-free activations: raw v_rcp_f32 + v_exp_f32 (1 instr each).
__device__ inline float fsigm(float x) {
  return __builtin_amdgcn_rcpf(1.f + __builtin_amdgcn_exp2f(-1.44269504f * x));
}
__device__ inline float ftanh(float x) {
  return 1.f - 2.f * __builtin_amdgcn_rcpf(1.f + __builtin_amdgcn_exp2f(2.88539008f * x));
}

// LDS-only barrier: waits LDS ops, does NOT drain vmcnt — global loads issued
// before this stay in flight across it (cross-wave data here is LDS-only).
__device__ inline void lds_barrier() {
  asm volatile("s_waitcnt lgkmcnt(0)\n\ts_barrier" ::: "memory");
}

// ============================================================================
// K1: gtab[v][c] = sum_e emb[v][e]*Wih_intra[c][e] + bih[c] (+bhh[c] folded for
// r,z gates). MFMA GEMM. 500 blocks own a 64-row emb tile and iterate ALL 6
// N-chunks (emb staged to LDS once -> ~6x less emb HBM fetch than the old
// 3000-block layout). Blocks 500..503: coalesced transpose of W_W_intra.
// ============================================================================
__global__ __launch_bounds__(256) void k_gtab(
    const float* __restrict__ emb,
    const float* __restrict__ wih,   // [768][128] fp32
    const float* __restrict__ bih,   // [768] fp32
    const float* __restrict__ bhh,   // [768] fp32 (r,z folded; n NOT)
    const float* __restrict__ wwi,   // [256][256] fp32 (h-major)
    unsigned short* __restrict__ gtab,   // [V][768] bf16
    unsigned short* __restrict__ wta)    // [256][256] bf16 (n-major)
{
  __shared__ __align__(16) unsigned short smem[64 * 264];  // union: alds / tbuf
  const int bid = blockIdx.x, tid = threadIdx.x;
  if (bid >= 500) {  // LDS-tiled transpose, 4 blocks x 64 n-rows
    const int n0 = (bid - 500) * 64;
    for (int i = 0; i < 64; ++i) {
      int cid = i * 256 + tid;
      int k = cid >> 6, nl = cid & 63;
      smem[nl * 264 + k] = f2b_rne(wwi[k * 256 + n0 + nl]);  // coalesced read
    }
    __syncthreads();
    for (int i = 0; i < 8; ++i) {
      int cid = i * 256 + tid;
      int nl = cid >> 5, k8 = cid & 31;
      *(int4*)&wta[(size_t)(n0 + nl) * 256 + k8 * 8] =
          *(const int4*)&smem[nl * 264 + k8 * 8];            // coalesced write
    }
    return;
  }
  const int vbase = bid * 64;
  for (int i = 0; i < 8; ++i) {
    int cid = i * 256 + tid;           // 2048 chunks of 4 floats
    int row = cid >> 5, kc = cid & 31;
    float4 v = *(const float4*)&emb[(size_t)(vbase + row) * 128 + kc * 4];
    ushort4 u;
    u.x = f2b_rne(v.x); u.y = f2b_rne(v.y); u.z = f2b_rne(v.z); u.w = f2b_rne(v.w);
    *(ushort4*)&smem[row * 136 + kc * 4] = u;
  }
  __syncthreads();
  const int w = tid >> 6, l = tid & 63, q = l >> 4, ln = l & 15;
  // hoist all A fragments (16 s8v = 64 VGPR) — reused across 6 N-chunks
  s8v af[4][4];
  for (int mt = 0; mt < 4; ++mt)
    for (int kf = 0; kf < 4; ++kf)
      af[mt][kf] = *(const s8v*)&smem[(mt * 16 + ln) * 136 + kf * 32 + q * 8];
  for (int nchunk = 0; nchunk < 6; ++nchunk) {
    const int nbase = nchunk * 128;
    s8v bf[2][4];
    float bias[2];
    for (int nt = 0; nt < 2; ++nt) {
      int c = nbase + (w * 2 + nt) * 16 + ln;
      int g = (c < 384) ? c : (c - 384);       // gate index within direction
      bias[nt] = bih[c] + (g < 256 ? bhh[c] : 0.f);  // fold r,z recurrent bias
      for (int kf = 0; kf < 4; ++kf)
        bf[nt][kf] = cvt8(&wih[(size_t)c * 128 + kf * 32 + q * 8]);
    }
    for (int mt = 0; mt < 4; ++mt) {
      for (int nt = 0; nt < 2; ++nt) {
        f32x4 acc = {0.f, 0.f, 0.f, 0.f};
        for (int kf = 0; kf < 4; ++kf) acc = mfma16(af[mt][kf], bf[nt][kf], acc);
        const int col = nbase + (w * 2 + nt) * 16 + ln;
        for (int r = 0; r < 4; ++r) {
          const int row = vbase + mt * 16 + q * 4 + r;
          gtab[(size_t)row * 768 + col] = f2b_rne(acc[r] + bias[nt]);
        }
      }
    }
  }
}

// ============================================================================
// K2: intra biGRU. Grid 256 = (s, dir, b-quad of 16). Double-buffered h in
// LDS, one LDS-only barrier/step. Token-gather software-pipelined at DEPTH 2:
// 4 rotating register buffers, inner loop fully unrolled x4 so all buffer
// indices are compile-time (no rotation moves -> no early vmcnt stall; a load
// issued at phase j is first read at phase j+2, ~2 step-times later).
// ============================================================================
__global__ __launch_bounds__(512) void k_intra(
    const int* __restrict__ tokens,
    const unsigned short* __restrict__ gtab,  // bf16, r/z biases folded
    const float* __restrict__ whh,            // [2][384][128] fp32
    const float* __restrict__ bhh,            // [2][384] fp32 (n-gate used)
    unsigned short* __restrict__ iout)        // [S*T*B][256] bf16 internal
{
  const int bid = blockIdx.x;
  const int s = bid >> 3, dir = (bid >> 2) & 1, bq = bid & 3;
  const int bbase = bq * 16;
  const int tid = threadIdx.x;
  const int w = tid >> 6, l = tid & 63, q = l >> 4, ln = l & 15;
  const int gbase = w * 16, g0 = gbase + q * 4;

  __shared__ __align__(16) unsigned short hb[2][16 * 136];
  __shared__ int tokl[T_ * 16];

  for (int i = tid; i < 2 * 16 * 136; i += 512) ((unsigned short*)hb)[i] = 0;
  for (int i = tid; i < T_ * 16; i += 512) {
    int t = i >> 4, bl = i & 15;
    tokl[i] = tokens[(s * T_ + t) * B_ + bbase + bl];
  }

  s8v af[3][4];
  float hbn[4];
  const float* whd = whh + (size_t)dir * (384 * 128);
  const float* bhd = bhh + dir * 384;
  for (int g3 = 0; g3 < 3; ++g3) {
    const int R = g3 * 128 + gbase;
    for (int kf = 0; kf < 4; ++kf)
      af[g3][kf] = cvt8(&whd[(size_t)(R + ln) * 128 + kf * 32 + q * 8]);
  }
  for (int r = 0; r < 4; ++r) hbn[r] = bhd[256 + gbase + q * 4 + r];  // n-gate only
  float h[4] = {0.f, 0.f, 0.f, 0.f};
  const int b = bbase + ln;
  __syncthreads();

  // --- depth-2 gather pipeline, 4 static register buffers ---
  ushort4 Xr[4], Xz[4], Xn[4];
#define GLOAD_I(slot, st)                                                   \
  do {                                                                      \
    int tt_ = (st) > (T_ - 1) ? (T_ - 1) : (st);                            \
    int tg_ = dir ? (T_ - 1 - tt_) : tt_;                                   \
    const unsigned short* gp_ =                                             \
        gtab + (size_t)tokl[tg_ * 16 + ln] * 768 + dir * 384 + g0;          \
    Xr[slot] = *(const ushort4*)&gp_[0];                                    \
    Xz[slot] = *(const ushort4*)&gp_[128];                                  \
    Xn[slot] = *(const ushort4*)&gp_[256];                                  \
  } while (0)

  GLOAD_I(0, 0);
  GLOAD_I(1, 1);

  int p = 0;
  for (int it = 0; it < T_ / 4; ++it) {
#pragma unroll
    for (int j = 0; j < 4; ++j) {
      const int step = it * 4 + j;
      const int t = dir ? (T_ - 1 - step) : step;
      GLOAD_I((j + 2) & 3, step + 2);   // prefetch 2 steps ahead

      s8v bfr[4];
      for (int kf = 0; kf < 4; ++kf)
        bfr[kf] = *(const s8v*)&hb[p][ln * 136 + kf * 32 + q * 8];
      f32x4 c0 = {0.f, 0.f, 0.f, 0.f}, c1 = c0, c2 = c0;
      for (int kf = 0; kf < 4; ++kf) {
        c0 = mfma16(af[0][kf], bfr[kf], c0);
        c1 = mfma16(af[1][kf], bfr[kf], c1);
        c2 = mfma16(af[2][kf], bfr[kf], c2);
      }

      const unsigned short* xrp = (const unsigned short*)&Xr[j];
      const unsigned short* xzp = (const unsigned short*)&Xz[j];
      const unsigned short* xnp = (const unsigned short*)&Xn[j];
      unsigned short hnb[4];
      for (int r = 0; r < 4; ++r) {
        float rr = fsigm(b2f(xrp[r]) + c0[r]);                 // bhh_r folded
        float zz = fsigm(b2f(xzp[r]) + c1[r]);                 // bhh_z folded
        float nn = ftanh(b2f(xnp[r]) + rr * (c2[r] + hbn[r])); // bhh_n inside r*()
        float hv = zz * (h[r] - nn) + nn;
        h[r] = hv;
        hnb[r] = f2b(hv);
      }
      ushort4 hv4; hv4.x = hnb[0]; hv4.y = hnb[1]; hv4.z = hnb[2]; hv4.w = hnb[3];
      *(ushort4*)&hb[p ^ 1][ln * 136 + g0] = hv4;
      *(ushort4*)&iout[((size_t)(s * T_ + t) * B_ + b) * 256 + dir * 128 + g0] = hv4;
      lds_barrier();
      p ^= 1;
    }
  }
#undef GLOAD_I
}

// ============================================================================
// K3 (fused attn): one pass over iout. Grid 256 = (s, b-group of 8).
// Full W_W_intra (256x256 bf16 = 128 KB) staged in LDS. Flash-style single
// iout read; cross-wave merge through the (then free) W LDS region.
// ============================================================================
__global__ __launch_bounds__(512, 1) void k_attn(
    const unsigned short* __restrict__ iout,  // bf16 internal
    const unsigned short* __restrict__ wta,   // bf16 [256][256] n-major
    const float* __restrict__ bint,           // [256] fp32
    const float* __restrict__ proj,           // [256] fp32
    float* __restrict__ sv)                   // [S*B][256] fp32
{
  __shared__ __align__(16) unsigned short wlds[256 * 256];  // 128 KB, XOR-swizzled
  __shared__ float lgbuf[8][16];
  __shared__ float lbuf[8][8];
  const int tid = threadIdx.x, bid = blockIdx.x;
  const int s = bid >> 3, b0 = (bid & 7) * 8;
  // stage full W (both halves), same swizzle as before
  for (int i = 0; i < 16; ++i) {
    int cid = i * 512 + tid;          // 8192 16B chunks
    int n = cid >> 5, kc = cid & 31;
    *(int4*)&wlds[n * 256 + ((kc ^ (n & 15)) << 3)] =
        *(const int4*)&wta[(size_t)n * 256 + kc * 8];
  }
  const int w = tid >> 6, l = tid & 63, q = l >> 4, ln = l & 15;
  float bbv[16], ppv[16];
  for (int nt = 0; nt < 16; ++nt) {     // per-lane bias/proj for its n-cols
    bbv[nt] = bint[nt * 16 + ln];
    ppv[nt] = proj[nt * 16 + ln];
  }
  __syncthreads();

  float O[8][8];                        // [kf][j] weighted-sum accumulator
  for (int kf = 0; kf < 8; ++kf)
    for (int j = 0; j < 8; ++j) O[kf][j] = 0.f;
  float l_acc = 0.f;

  for (int tile = 0; tile < 4; ++tile) {  // wave w owns t = 8w .. 8w+7
    const int t = (w * 4 + tile) * 2 + (ln >> 3);
    const size_t row = (size_t)((s * T_ + t) * B_ + b0 + (ln & 7));
    s8v af[8];
    for (int kf = 0; kf < 8; ++kf)
      af[kf] = *(const s8v*)&iout[row * 256 + kf * 32 + q * 8];
    float p0 = 0.f, p1 = 0.f, p2 = 0.f, p3 = 0.f;
    for (int nt = 0; nt < 16; ++nt) {
      f32x4 c = {0.f, 0.f, 0.f, 0.f};
      for (int kf = 0; kf < 8; ++kf) {
        s8v bf = *(const s8v*)&wlds[(nt * 16 + ln) * 256 + (((kf * 4 + q) ^ ln) << 3)];
        c = mfma16(af[kf], bf, c);
      }
      p0 += ppv[nt] * ftanh(c[0] + bbv[nt]);
      p1 += ppv[nt] * ftanh(c[1] + bbv[nt]);
      p2 += ppv[nt] * ftanh(c[2] + bbv[nt]);
      p3 += ppv[nt] * ftanh(c[3] + bbv[nt]);
    }
    for (int d = 1; d < 16; d <<= 1) {   // reduce over n-col lanes
      p0 += __shfl_xor(p0, d); p1 += __shfl_xor(p1, d);
      p2 += __shfl_xor(p2, d); p3 += __shfl_xor(p3, d);
    }
    // remap logits (held per D-row q*4+r) to A-row layout via same-wave LDS
    if (ln == 0) {
      lgbuf[w][q * 4 + 0] = p0; lgbuf[w][q * 4 + 1] = p1;
      lgbuf[w][q * 4 + 2] = p2; lgbuf[w][q * 4 + 3] = p3;
    }
    const float lg = lgbuf[w][ln];       // logit for THIS lane's (t,b) row
    const float e = __builtin_amdgcn_exp2f(1.44269504f * lg);
    l_acc += e;
    for (int kf = 0; kf < 8; ++kf)
      for (int j = 0; j < 8; ++j)
        O[kf][j] += e * b2f((unsigned short)af[kf][j]);
  }
  // merge t-pair lanes (ln, ln+8): same b, same dims
  l_acc += __shfl_xor(l_acc, 8);
  for (int kf = 0; kf < 8; ++kf)
    for (int j = 0; j < 8; ++j) O[kf][j] += __shfl_xor(O[kf][j], 8);
  __syncthreads();                       // everyone done reading wlds
  float* obuf = (float*)wlds;            // overlay: [8 waves][8 b][256 d]
  if (ln < 8) {
    const int base = w * 2048 + ln * 256 + q * 8;
    for (int kf = 0; kf < 8; ++kf) {
      float4 v0; v0.x = O[kf][0]; v0.y = O[kf][1]; v0.z = O[kf][2]; v0.w = O[kf][3];
      float4 v1; v1.x = O[kf][4]; v1.y = O[kf][5]; v1.z = O[kf][6]; v1.w = O[kf][7];
      *(float4*)&obuf[base + kf * 32]     = v0;
      *(float4*)&obuf[base + kf * 32 + 4] = v1;
    }
    if (q == 0) lbuf[w][ln] = l_acc;
  }
  __syncthreads();
  // deterministic 8-way reduce + softmax normalize + store sv
  const int idx = tid * 4;               // 2048 outputs / 512 threads
  const int bb_ = idx >> 8;
  float4 acc; acc.x = 0.f; acc.y = 0.f; acc.z = 0.f; acc.w = 0.f;
  float lsum = 0.f;
  for (int w8 = 0; w8 < 8; ++w8) {
    const float4 v = *(const float4*)&obuf[w8 * 2048 + idx];
    acc.x += v.x; acc.y += v.y; acc.z += v.z; acc.w += v.w;
    lsum += lbuf[w8][bb_];
  }
  const float inv = __builtin_amdgcn_rcpf(lsum);
  float4 r; r.x = acc.x * inv; r.y = acc.y * inv; r.z = acc.z * inv; r.w = acc.w * inv;
  *(float4*)&sv[(size_t)((s * B_ + b0 + bb_) * 256) + (idx & 255)] = r;
}

// ============================================================================
// K4: inter input gates xgi = sv @ Wih_inter^T + bih_inter (+bhh r,z folded)
// ============================================================================
__global__ __launch_bounds__(256) void k_xgi(
    const float* __restrict__ sv,
    const float* __restrict__ wihI,  // [768][256] fp32
    const float* __restrict__ bihI,  // [768] fp32
    const float* __restrict__ bhhI,  // [768] fp32
    float* __restrict__ xgi)         // [2][2048][384]
{
  const int bid = blockIdx.x, tid = threadIdx.x;
  const int r0 = bid * 8;
  __shared__ float svl[8 * 256];
  for (int i = 0; i < 8; ++i) svl[i * 256 + tid] = sv[(size_t)(r0 + i) * 256 + tid];
  __syncthreads();
  for (int cc = 0; cc < 3; ++cc) {
    const int c = cc * 256 + tid;
    const int dir = c / 384, g = c - dir * 384;
    const float bias = bihI[c] + (g < 256 ? bhhI[c] : 0.f);  // fold r,z
    float acc[8];
    for (int i = 0; i < 8; ++i) acc[i] = bias;
    const float* wr = wihI + (size_t)c * 256;
    for (int hh = 0; hh < 256; ++hh) {
      const float wv = wr[hh];
      for (int i = 0; i < 8; ++i) acc[i] += wv * svl[i * 256 + hh];
    }
    for (int i = 0; i < 8; ++i)
      xgi[((size_t)dir * 2048 + r0 + i) * 384 + g] = acc[i];
  }
}

// ============================================================================
// K5: inter biGRU. Grid 8 = (dir, b-quad of 16). Same depth-2 pipelined
// structure as K2 (cold fp32 xgi loads hidden 2 steps deep).
// ============================================================================
__global__ __launch_bounds__(512) void k_inter(
    const float* __restrict__ xgi,   // r,z biases folded
    const float* __restrict__ whh,   // [2][384][128] fp32
    const float* __restrict__ bhh,   // [2][384] fp32 (n-gate used)
    float* __restrict__ io2)         // [S*B][256] fp32
{
  const int bid = blockIdx.x;
  const int dir = bid >> 2, bq = bid & 3, bbase = bq * 16;
  const int tid = threadIdx.x;
  const int w = tid >> 6, l = tid & 63, q = l >> 4, ln = l & 15;
  const int gbase = w * 16, g0 = gbase + q * 4;
  __shared__ __align__(16) unsigned short hb[2][16 * 136];
  for (int i = tid; i < 2 * 16 * 136; i += 512) ((unsigned short*)hb)[i] = 0;
  s8v af[3][4];
  float hbn[4];
  const float* whd = whh + (size_t)dir * (384 * 128);
  const float* bhd = bhh + dir * 384;
  for (int g3 = 0; g3 < 3; ++g3) {
    const int R = g3 * 128 + gbase;
    for (int kf = 0; kf < 4; ++kf)
      af[g3][kf] = cvt8(&whd[(size_t)(R + ln) * 128 + kf * 32 + q * 8]);
  }
  for (int r = 0; r < 4; ++r) hbn[r] = bhd[256 + gbase + q * 4 + r];
  float h[4] = {0.f, 0.f, 0.f, 0.f};
  const int b = bbase + ln;
  __syncthreads();

  float4 Vr[4], Vz[4], Vn[4];
#define GLOAD_S(slot, st)                                                   \
  do {                                                                      \
    int tt_ = (st) > (S_ - 1) ? (S_ - 1) : (st);                            \
    int sg_ = dir ? (S_ - 1 - tt_) : tt_;                                   \
    const float* xp_ = xgi + ((size_t)dir * 2048 + sg_ * 64 + b) * 384 + g0;\
    Vr[slot] = *(const float4*)&xp_[0];                                     \
    Vz[slot] = *(const float4*)&xp_[128];                                   \
    Vn[slot] = *(const float4*)&xp_[256];                                   \
  } while (0)

  GLOAD_S(0, 0);
  GLOAD_S(1, 1);

  int p = 0;
  for (int it = 0; it < S_ / 4; ++it) {
#pragma unroll
    for (int j = 0; j < 4; ++j) {
      const int step = it * 4 + j;
      const int sI = dir ? (S_ - 1 - step) : step;
      GLOAD_S((j + 2) & 3, step + 2);

      s8v bfr[4];
      for (int kf = 0; kf < 4; ++kf)
        bfr[kf] = *(const s8v*)&hb[p][ln * 136 + kf * 32 + q * 8];
      f32x4 c0 = {0.f, 0.f, 0.f, 0.f}, c1 = c0, c2 = c0;
      for (int kf = 0; kf < 4; ++kf) {
        c0 = mfma16(af[0][kf], bfr[kf], c0);
        c1 = mfma16(af[1][kf], bfr[kf], c1);
        c2 = mfma16(af[2][kf], bfr[kf], c2);
      }
      const float irv[4] = {Vr[j].x, Vr[j].y, Vr[j].z, Vr[j].w};
      const float izv[4] = {Vz[j].x, Vz[j].y, Vz[j].z, Vz[j].w};
      const float inv[4] = {Vn[j].x, Vn[j].y, Vn[j].z, Vn[j].w};
      unsigned short hnb[4];
      for (int r = 0; r < 4; ++r) {
        float rr = fsigm(irv[r] + c0[r]);
        float zz = fsigm(izv[r] + c1[r]);
        float nn = ftanh(inv[r] + rr * (c2[r] + hbn[r]));
        float hv = zz * (h[r] - nn) + nn;
        h[r] = hv;
        hnb[r] = f2b(hv);
      }
      ushort4 hv4; hv4.x = hnb[0]; hv4.y = hnb[1]; hv4.z = hnb[2]; hv4.w = hnb[3];
      *(ushort4*)&hb[p ^ 1][ln * 136 + g0] = hv4;
      float4 of4; of4.x = h[0]; of4.y = h[1]; of4.z = h[2]; of4.w = h[3];
      *(float4*)&io2[((size_t)(sI * 64 + b)) * 256 + dir * 128 + g0] = of4;
      lds_barrier();
      p ^= 1;
    }
  }
#undef GLOAD_S
}

// ============================================================================
// K6: a2[s*64+b] = proj_inter . tanh(io2 @ W_W_inter + b_inter)  (no softmax)
// ============================================================================
__global__ __launch_bounds__(256) void k_attn_i(
    const float* __restrict__ io2,
    const float* __restrict__ wwI,   // [256][256] fp32 h-major
    const float* __restrict__ bI,
    const float* __restrict__ projI,
    float* __restrict__ a2)          // [2048]
{
  const int bid = blockIdx.x, tid = threadIdx.x;
  const int r0 = bid * 8;
  __shared__ float iol[8 * 256];
  __shared__ float red[4 * 8];
  for (int i = 0; i < 8; ++i) iol[i * 256 + tid] = io2[(size_t)(r0 + i) * 256 + tid];
  __syncthreads();
  float acc[8];
  for (int i = 0; i < 8; ++i) acc[i] = 0.f;
  for (int hh = 0; hh < 256; ++hh) {
    const float wv = wwI[hh * 256 + tid];
    for (int i = 0; i < 8; ++i) acc[i] += wv * iol[i * 256 + hh];
  }
  const float bb = bI[tid], pp = projI[tid];
  float p[8];
  for (int i = 0; i < 8; ++i) p[i] = pp * ftanh(acc[i] + bb);
  for (int d = 1; d < 64; d <<= 1)
    for (int i = 0; i < 8; ++i) p[i] += __shfl_xor(p[i], d);
  const int w = tid >> 6, l = tid & 63;
  if (l == 0)
    for (int i = 0; i < 8; ++i) red[w * 8 + i] = p[i];
  __syncthreads();
  if (tid < 8) a2[r0 + tid] = red[tid] + red[8 + tid] + red[16 + tid] + red[24 + tid];
}

// ============================================================================
// K7: doc_vec = sum_s a2 * io2 ; out = doc @ W_final^T + b_final  (fp32 out)
// ============================================================================
__global__ __launch_bounds__(256) void k_final(
    const float* __restrict__ a2,
    const float* __restrict__ io2,
    const float* __restrict__ wf,    // [5][256] fp32
    const float* __restrict__ bfi,   // [5] fp32
    float* __restrict__ out)         // [64][5] fp32
{
  const int b = blockIdx.x, tid = threadIdx.x;
  __shared__ float av[S_];
  __shared__ float dv[256];
  __shared__ float red[4];
  if (tid < S_) av[tid] = a2[tid * 64 + b];
  __syncthreads();
  float acc = 0.f;
  for (int s = 0; s < S_; ++s) acc += av[s] * io2[((size_t)(s * 64 + b)) * 256 + tid];
  dv[tid] = acc;
  __syncthreads();
  for (int c = 0; c < C_; ++c) {
    float pv = wf[c * 256 + tid] * dv[tid];
    for (int d = 1; d < 64; d <<= 1) pv += __shfl_xor(pv, d);
    const int w = tid >> 6, l = tid & 63;
    if (l == 0) red[w] = pv;
    __syncthreads();
    if (tid == 0)
      out[b * C_ + c] = red[0] + red[1] + red[2] + red[3] + bfi[c];
    __syncthreads();
  }
}

// ============================================================================
extern "C" void kernel_launch(void* const* d_in, const int* in_sizes, int n_in,
                              void* d_out, int out_size, void* d_ws, size_t ws_size,
                              hipStream_t stream) {
  (void)in_sizes; (void)n_in; (void)out_size; (void)ws_size;
  const int*   tokens = (const int*)d_in[0];
  const float* emb    = (const float*)d_in[1];
  const float* wih_a  = (const float*)d_in[2];
  const float* whh_a  = (const float*)d_in[3];
  const float* bih_a  = (const float*)d_in[4];
  const float* bhh_a  = (const float*)d_in[5];
  const float* ww_a   = (const float*)d_in[6];
  const float* b_a    = (const float*)d_in[7];
  const float* proj_a = (const float*)d_in[8];
  const float* wih_i  = (const float*)d_in[9];
  const float* whh_i  = (const float*)d_in[10];
  const float* bih_i  = (const float*)d_in[11];
  const float* bhh_i  = (const float*)d_in[12];
  const float* ww_i   = (const float*)d_in[13];
  const float* b_i    = (const float*)d_in[14];
  const float* proj_i = (const float*)d_in[15];
  const float* w_fin  = (const float*)d_in[16];
  const float* b_fin  = (const float*)d_in[17];

  char* ws = (char*)d_ws;
  unsigned short* gtab = (unsigned short*)(ws + 0);          // 49,152,000 B
  unsigned short* wta  = (unsigned short*)(ws + 49152000);   //    131,072 B
  unsigned short* iout = (unsigned short*)(ws + 49283072);   // 67,108,864 B
  float* sv  = (float*)(ws + 117440512);                     //  2,097,152 B
  float* xgi = (float*)(ws + 119537664);                     //  6,291,456 B
  float* io2 = (float*)(ws + 125829120);                     //  2,097,152 B
  float* a2  = (float*)(ws + 127926272);                     //      8,192 B

  k_gtab<<<504, 256, 0, stream>>>(emb, wih_a, bih_a, bhh_a, ww_a, gtab, wta);
  k_intra<<<256, 512, 0, stream>>>(tokens, gtab, whh_a, bhh_a, iout);
  k_attn<<<256, 512, 0, stream>>>(iout, wta, b_a, proj_a, sv);
  k_xgi<<<256, 256, 0, stream>>>(sv, wih_i, bih_i, bhh_i, xgi);
  k_inter<<<8, 512, 0, stream>>>(xgi, whh_i, bhh_i, io2);
  k_attn_i<<<256, 256, 0, stream>>>(io2, ww_i, b_i, proj_i, a2);
  k_final<<<64, 256, 0, stream>>>(a2, io2, w_fin, b_fin, (float*)d_out);
}

// Round 3
// 289.624 us; speedup vs baseline: 1.2658x; 1.0766x over previous
//
#include <hip/hip_runtime.h>

// Problem dims
#define S_ 32
#define T_ 64
#define B_ 64
#define V_ 32000
#define E_ 128
#define H_ 128
#define G_ 128
#define C_ 5

typedef short s8v __attribute__((ext_vector_type(8)));   // 8 bf16 payload
typedef __bf16 b8v __attribute__((ext_vector_type(8)));
typedef float f32x4 __attribute__((ext_vector_type(4)));

// --- MFMA wrapper: tolerate either builtin operand signature (short8 or bf16x8)
template <typename V>
__device__ inline auto mfma_sel(V a, V b, f32x4 c, int)
    -> decltype(__builtin_amdgcn_mfma_f32_16x16x32_bf16(a, b, c, 0, 0, 0)) {
  return __builtin_amdgcn_mfma_f32_16x16x32_bf16(a, b, c, 0, 0, 0);
}
template <typename V>
__device__ inline f32x4 mfma_sel(V a, V b, f32x4 c, long) {
  return __builtin_amdgcn_mfma_f32_16x16x32_bf16(
      __builtin_bit_cast(b8v, a), __builtin_bit_cast(b8v, b), c, 0, 0, 0);
}
__device__ inline f32x4 mfma16(s8v a, s8v b, f32x4 c) { return mfma_sel(a, b, c, 0); }

__device__ inline float b2f(unsigned short u) {
  union { unsigned int i; float f; } v; v.i = ((unsigned int)u) << 16; return v.f;
}
// round-to-nearest (ties away) — 2 instr; RNE tie diff is <=1ulp, irrelevant at 2% tol
__device__ inline unsigned short f2b(float f) {
  union { float f; unsigned int i; } v; v.f = f;
  return (unsigned short)((v.i + 0x8000u) >> 16);
}
// full-RNE for the precomputed tables (cheap there, done once per element)
__device__ inline unsigned short f2b_rne(float f) {
  union { float f; unsigned int i; } v; v.f = f;
  unsigned int r = (v.i + 0x7fffu + ((v.i >> 16) & 1u)) >> 16;
  return (unsigned short)r;
}
__device__ inline s8v cvt8(const float* p) {
  const float4 a = *(const float4*)p;
  const float4 b = *(const float4*)(p + 4);
  s8v r;
  r[0] = (short)f2b_rne(a.x); r[1] = (short)f2b_rne(a.y);
  r[2] = (short)f2b_rne(a.z); r[3] = (short)f2b_rne(a.w);
  r[4] = (short)f2b_rne(b.x); r[5] = (short)f2b_rne(b.y);
  r[6] = (short)f2b_rne(b.z); r[7] = (short)f2b_rne(b.w);
  return r;
}
// division-free activations: raw v_rcp_f32 + v_exp_f32 (1 instr each).
__device__ inline float fsigm(float x) {
  return __builtin_amdgcn_rcpf(1.f + __builtin_amdgcn_exp2f(-1.44269504f * x));
}
__device__ inline float ftanh(float x) {
  return 1.f - 2.f * __builtin_amdgcn_rcpf(1.f + __builtin_amdgcn_exp2f(2.88539008f * x));
}

// LDS-only barrier: waits LDS ops, does NOT drain vmcnt — global loads issued
// before this stay in flight across it (cross-wave data here is LDS-only).
__device__ inline void lds_barrier() {
  asm volatile("s_waitcnt lgkmcnt(0)\n\ts_barrier" ::: "memory");
}

// ============================================================================
// K1: gtab[v][c] = sum_e emb[v][e]*Wih_intra[c][e] + bih[c] (+bhh[c] folded for
// r,z gates). MFMA GEMM: 500 blocks own a 64-row emb tile and iterate ALL 6
// N-chunks. Blocks 500..503: transpose W_W_intra. Blocks 504..507: convert
// Wih_inter fp32 -> bf16 (for the fused xgi MFMA in k_attn).
// ============================================================================
__global__ __launch_bounds__(256) void k_gtab(
    const float* __restrict__ emb,
    const float* __restrict__ wih,   // [768][128] fp32
    const float* __restrict__ bih,   // [768] fp32
    const float* __restrict__ bhh,   // [768] fp32 (r,z folded; n NOT)
    const float* __restrict__ wwi,   // [256][256] fp32 (h-major)
    const float* __restrict__ wihI,  // [768][256] fp32 (inter input weights)
    unsigned short* __restrict__ gtab,   // [V][768] bf16
    unsigned short* __restrict__ wta,    // [256][256] bf16 (n-major)
    unsigned short* __restrict__ wib)    // [768][256] bf16
{
  __shared__ __align__(16) unsigned short smem[64 * 264];  // union: alds / tbuf
  const int bid = blockIdx.x, tid = threadIdx.x;
  if (bid >= 504) {  // wihI fp32 -> bf16, 4 blocks
    const int cb = bid - 504;
    for (int i = 0; i < 48; ++i) {
      int e4 = cb * 12288 + i * 256 + tid;  // float4 index
      float4 v = *(const float4*)&wihI[(size_t)e4 * 4];
      ushort4 u;
      u.x = f2b_rne(v.x); u.y = f2b_rne(v.y); u.z = f2b_rne(v.z); u.w = f2b_rne(v.w);
      *(ushort4*)&wib[(size_t)e4 * 4] = u;
    }
    return;
  }
  if (bid >= 500) {  // LDS-tiled transpose, 4 blocks x 64 n-rows
    const int n0 = (bid - 500) * 64;
    for (int i = 0; i < 64; ++i) {
      int cid = i * 256 + tid;
      int k = cid >> 6, nl = cid & 63;
      smem[nl * 264 + k] = f2b_rne(wwi[k * 256 + n0 + nl]);  // coalesced read
    }
    __syncthreads();
    for (int i = 0; i < 8; ++i) {
      int cid = i * 256 + tid;
      int nl = cid >> 5, k8 = cid & 31;
      *(int4*)&wta[(size_t)(n0 + nl) * 256 + k8 * 8] =
          *(const int4*)&smem[nl * 264 + k8 * 8];            // coalesced write
    }
    return;
  }
  const int vbase = bid * 64;
  for (int i = 0; i < 8; ++i) {
    int cid = i * 256 + tid;           // 2048 chunks of 4 floats
    int row = cid >> 5, kc = cid & 31;
    float4 v = *(const float4*)&emb[(size_t)(vbase + row) * 128 + kc * 4];
    ushort4 u;
    u.x = f2b_rne(v.x); u.y = f2b_rne(v.y); u.z = f2b_rne(v.z); u.w = f2b_rne(v.w);
    *(ushort4*)&smem[row * 136 + kc * 4] = u;
  }
  __syncthreads();
  const int w = tid >> 6, l = tid & 63, q = l >> 4, ln = l & 15;
  // hoist all A fragments (16 s8v = 64 VGPR) — reused across 6 N-chunks
  s8v af[4][4];
  for (int mt = 0; mt < 4; ++mt)
    for (int kf = 0; kf < 4; ++kf)
      af[mt][kf] = *(const s8v*)&smem[(mt * 16 + ln) * 136 + kf * 32 + q * 8];
  for (int nchunk = 0; nchunk < 6; ++nchunk) {
    const int nbase = nchunk * 128;
    s8v bf[2][4];
    float bias[2];
    for (int nt = 0; nt < 2; ++nt) {
      int c = nbase + (w * 2 + nt) * 16 + ln;
      int g = (c < 384) ? c : (c - 384);       // gate index within direction
      bias[nt] = bih[c] + (g < 256 ? bhh[c] : 0.f);  // fold r,z recurrent bias
      for (int kf = 0; kf < 4; ++kf)
        bf[nt][kf] = cvt8(&wih[(size_t)c * 128 + kf * 32 + q * 8]);
    }
    for (int mt = 0; mt < 4; ++mt) {
      for (int nt = 0; nt < 2; ++nt) {
        f32x4 acc = {0.f, 0.f, 0.f, 0.f};
        for (int kf = 0; kf < 4; ++kf) acc = mfma16(af[mt][kf], bf[nt][kf], acc);
        const int col = nbase + (w * 2 + nt) * 16 + ln;
        for (int r = 0; r < 4; ++r) {
          const int row = vbase + mt * 16 + q * 4 + r;
          gtab[(size_t)row * 768 + col] = f2b_rne(acc[r] + bias[nt]);
        }
      }
    }
  }
}

// ============================================================================
// K2: intra biGRU. Grid 256 = (s, dir, b-quad of 16). Double-buffered h in
// LDS, one LDS-only barrier/step. Token-gather software-pipelined at DEPTH 3:
// 4 static register slots, loop unrolled x4 (all indices compile-time). Slot
// (j+3)&3 written at step j was last read at step j-1 -> WAR-safe. tokl holds
// prescaled row offsets (token*768 + dir*384) to keep addr math off the path.
// ============================================================================
__global__ __launch_bounds__(512) void k_intra(
    const int* __restrict__ tokens,
    const unsigned short* __restrict__ gtab,  // bf16, r/z biases folded
    const float* __restrict__ whh,            // [2][384][128] fp32
    const float* __restrict__ bhh,            // [2][384] fp32 (n-gate used)
    unsigned short* __restrict__ iout)        // [S*T*B][256] bf16 internal
{
  const int bid = blockIdx.x;
  const int s = bid >> 3, dir = (bid >> 2) & 1, bq = bid & 3;
  const int bbase = bq * 16;
  const int tid = threadIdx.x;
  const int w = tid >> 6, l = tid & 63, q = l >> 4, ln = l & 15;
  const int gbase = w * 16, g0 = gbase + q * 4;

  __shared__ __align__(16) unsigned short hb[2][16 * 136];
  __shared__ int tokl[T_ * 16];

  for (int i = tid; i < 2 * 16 * 136; i += 512) ((unsigned short*)hb)[i] = 0;
  for (int i = tid; i < T_ * 16; i += 512) {
    int t = i >> 4, bl = i & 15;
    tokl[i] = tokens[(s * T_ + t) * B_ + bbase + bl] * 768 + dir * 384;
  }

  s8v af[3][4];
  float hbn[4];
  const float* whd = whh + (size_t)dir * (384 * 128);
  const float* bhd = bhh + dir * 384;
  for (int g3 = 0; g3 < 3; ++g3) {
    const int R = g3 * 128 + gbase;
    for (int kf = 0; kf < 4; ++kf)
      af[g3][kf] = cvt8(&whd[(size_t)(R + ln) * 128 + kf * 32 + q * 8]);
  }
  for (int r = 0; r < 4; ++r) hbn[r] = bhd[256 + gbase + q * 4 + r];  // n-gate only
  float h[4] = {0.f, 0.f, 0.f, 0.f};
  const int b = bbase + ln;
  __syncthreads();

  // --- depth-3 gather pipeline, 4 static register slots ---
  ushort4 Xr[4], Xz[4], Xn[4];
#define GLOAD_I(slot, st)                                                   \
  do {                                                                      \
    int tt_ = (st) > (T_ - 1) ? (T_ - 1) : (st);                            \
    int tg_ = dir ? (T_ - 1 - tt_) : tt_;                                   \
    const unsigned short* gp_ =                                             \
        gtab + (size_t)(tokl[tg_ * 16 + ln] + g0);                          \
    Xr[slot] = *(const ushort4*)&gp_[0];                                    \
    Xz[slot] = *(const ushort4*)&gp_[128];                                  \
    Xn[slot] = *(const ushort4*)&gp_[256];                                  \
  } while (0)

  GLOAD_I(0, 0);
  GLOAD_I(1, 1);
  GLOAD_I(2, 2);

  int p = 0;
  for (int it = 0; it < T_ / 4; ++it) {
#pragma unroll
    for (int j = 0; j < 4; ++j) {
      const int step = it * 4 + j;
      const int t = dir ? (T_ - 1 - step) : step;
      GLOAD_I((j + 3) & 3, step + 3);   // prefetch 3 steps ahead

      s8v bfr[4];
      for (int kf = 0; kf < 4; ++kf)
        bfr[kf] = *(const s8v*)&hb[p][ln * 136 + kf * 32 + q * 8];
      f32x4 c0 = {0.f, 0.f, 0.f, 0.f}, c1 = c0, c2 = c0;
      for (int kf = 0; kf < 4; ++kf) {
        c0 = mfma16(af[0][kf], bfr[kf], c0);
        c1 = mfma16(af[1][kf], bfr[kf], c1);
        c2 = mfma16(af[2][kf], bfr[kf], c2);
      }

      const unsigned short* xrp = (const unsigned short*)&Xr[j];
      const unsigned short* xzp = (const unsigned short*)&Xz[j];
      const unsigned short* xnp = (const unsigned short*)&Xn[j];
      unsigned short hnb[4];
      for (int r = 0; r < 4; ++r) {
        float rr = fsigm(b2f(xrp[r]) + c0[r]);                 // bhh_r folded
        float zz = fsigm(b2f(xzp[r]) + c1[r]);                 // bhh_z folded
        float nn = ftanh(b2f(xnp[r]) + rr * (c2[r] + hbn[r])); // bhh_n inside r*()
        float hv = zz * (h[r] - nn) + nn;
        h[r] = hv;
        hnb[r] = f2b(hv);
      }
      ushort4 hv4; hv4.x = hnb[0]; hv4.y = hnb[1]; hv4.z = hnb[2]; hv4.w = hnb[3];
      *(ushort4*)&hb[p ^ 1][ln * 136 + g0] = hv4;
      *(ushort4*)&iout[((size_t)(s * T_ + t) * B_ + b) * 256 + dir * 128 + g0] = hv4;
      lds_barrier();
      p ^= 1;
    }
  }
#undef GLOAD_I
}

// ============================================================================
// K3 (fused attn + xgi): one pass over iout. Grid 256 = (s, b-group of 8).
// Full W_W_intra (128 KB) in LDS; flash-style single iout read; cross-wave
// merge through the freed W region; THEN the inter input-gate GEMM
// (xgi = sv @ WihI^T + biases) fused on the block's 8 sv rows via bf16 MFMA.
// ============================================================================
__global__ __launch_bounds__(512, 1) void k_attn(
    const unsigned short* __restrict__ iout,  // bf16 internal
    const unsigned short* __restrict__ wta,   // bf16 [256][256] n-major
    const float* __restrict__ bint,           // [256] fp32
    const float* __restrict__ proj,           // [256] fp32
    const unsigned short* __restrict__ wib,   // bf16 [768][256] (WihI)
    const float* __restrict__ bihI,           // [768] fp32
    const float* __restrict__ bhhI,           // [768] fp32
    float* __restrict__ xgi)                  // [2][2048][384] fp32
{
  __shared__ __align__(16) unsigned short wlds[256 * 256];  // 128 KB, XOR-swizzled
  __shared__ float lgbuf[8][16];
  __shared__ float lbuf[8][8];
  const int tid = threadIdx.x, bid = blockIdx.x;
  const int s = bid >> 3, b0 = (bid & 7) * 8;
  // stage full W (both halves)
  for (int i = 0; i < 16; ++i) {
    int cid = i * 512 + tid;          // 8192 16B chunks
    int n = cid >> 5, kc = cid & 31;
    *(int4*)&wlds[n * 256 + ((kc ^ (n & 15)) << 3)] =
        *(const int4*)&wta[(size_t)n * 256 + kc * 8];
  }
  const int w = tid >> 6, l = tid & 63, q = l >> 4, ln = l & 15;
  float bbv[16], ppv[16];
  for (int nt = 0; nt < 16; ++nt) {     // per-lane bias/proj for its n-cols
    bbv[nt] = bint[nt * 16 + ln];
    ppv[nt] = proj[nt * 16 + ln];
  }
  __syncthreads();

  float O[8][8];                        // [kf][j] weighted-sum accumulator
  for (int kf = 0; kf < 8; ++kf)
    for (int j = 0; j < 8; ++j) O[kf][j] = 0.f;
  float l_acc = 0.f;

  for (int tile = 0; tile < 4; ++tile) {  // wave w owns t = 8w .. 8w+7
    const int t = (w * 4 + tile) * 2 + (ln >> 3);
    const size_t row = (size_t)((s * T_ + t) * B_ + b0 + (ln & 7));
    s8v af[8];
    for (int kf = 0; kf < 8; ++kf)
      af[kf] = *(const s8v*)&iout[row * 256 + kf * 32 + q * 8];
    float p0 = 0.f, p1 = 0.f, p2 = 0.f, p3 = 0.f;
    for (int nt = 0; nt < 16; ++nt) {
      f32x4 c = {0.f, 0.f, 0.f, 0.f};
      for (int kf = 0; kf < 8; ++kf) {
        s8v bf = *(const s8v*)&wlds[(nt * 16 + ln) * 256 + (((kf * 4 + q) ^ ln) << 3)];
        c = mfma16(af[kf], bf, c);
      }
      p0 += ppv[nt] * ftanh(c[0] + bbv[nt]);
      p1 += ppv[nt] * ftanh(c[1] + bbv[nt]);
      p2 += ppv[nt] * ftanh(c[2] + bbv[nt]);
      p3 += ppv[nt] * ftanh(c[3] + bbv[nt]);
    }
    for (int d = 1; d < 16; d <<= 1) {   // reduce over n-col lanes
      p0 += __shfl_xor(p0, d); p1 += __shfl_xor(p1, d);
      p2 += __shfl_xor(p2, d); p3 += __shfl_xor(p3, d);
    }
    // remap logits (held per D-row q*4+r) to A-row layout via same-wave LDS
    if (ln == 0) {
      lgbuf[w][q * 4 + 0] = p0; lgbuf[w][q * 4 + 1] = p1;
      lgbuf[w][q * 4 + 2] = p2; lgbuf[w][q * 4 + 3] = p3;
    }
    const float lg = lgbuf[w][ln];       // logit for THIS lane's (t,b) row
    const float e = __builtin_amdgcn_exp2f(1.44269504f * lg);
    l_acc += e;
    for (int kf = 0; kf < 8; ++kf)
      for (int j = 0; j < 8; ++j)
        O[kf][j] += e * b2f((unsigned short)af[kf][j]);
  }
  // merge t-pair lanes (ln, ln+8): same b, same dims
  l_acc += __shfl_xor(l_acc, 8);
  for (int kf = 0; kf < 8; ++kf)
    for (int j = 0; j < 8; ++j) O[kf][j] += __shfl_xor(O[kf][j], 8);
  __syncthreads();                       // everyone done reading wlds
  float* obuf = (float*)wlds;            // overlay [0..64K): [8 waves][8 b][256 d]
  unsigned short* svl = (unsigned short*)(((char*)wlds) + 65536);  // [16][264] bf16
  if (ln < 8) {
    const int base = w * 2048 + ln * 256 + q * 8;
    for (int kf = 0; kf < 8; ++kf) {
      float4 v0; v0.x = O[kf][0]; v0.y = O[kf][1]; v0.z = O[kf][2]; v0.w = O[kf][3];
      float4 v1; v1.x = O[kf][4]; v1.y = O[kf][5]; v1.z = O[kf][6]; v1.w = O[kf][7];
      *(float4*)&obuf[base + kf * 32]     = v0;
      *(float4*)&obuf[base + kf * 32 + 4] = v1;
    }
    if (q == 0) lbuf[w][ln] = l_acc;
  }
  // zero pad rows 8..15 of svl (A-operand padding for the M=8 GEMM)
  {
    ushort4 z4; z4.x = 0; z4.y = 0; z4.z = 0; z4.w = 0;
    int rr = 8 + (tid >> 6), cc = (tid & 63) * 4;  // 8 rows x 256 cols, pad ignored
    *(ushort4*)&svl[rr * 264 + cc] = z4;
  }
  __syncthreads();
  // deterministic 8-way reduce + softmax normalize -> sv (bf16, into svl)
  const int idx = tid * 4;               // 2048 outputs / 512 threads
  const int bb_ = idx >> 8;
  float4 acc; acc.x = 0.f; acc.y = 0.f; acc.z = 0.f; acc.w = 0.f;
  float lsum = 0.f;
  for (int w8 = 0; w8 < 8; ++w8) {
    const float4 v = *(const float4*)&obuf[w8 * 2048 + idx];
    acc.x += v.x; acc.y += v.y; acc.z += v.z; acc.w += v.w;
    lsum += lbuf[w8][bb_];
  }
  const float inv = __builtin_amdgcn_rcpf(lsum);
  ushort4 u;
  u.x = f2b_rne(acc.x * inv); u.y = f2b_rne(acc.y * inv);
  u.z = f2b_rne(acc.z * inv); u.w = f2b_rne(acc.w * inv);
  *(ushort4*)&svl[bb_ * 264 + (idx & 255)] = u;
  __syncthreads();
  // ---- fused xgi GEMM: out[m=0..7][c=0..767] = sv . WihI[c] + bias ----
  s8v afx[8];
  for (int kf = 0; kf < 8; ++kf)
    afx[kf] = *(const s8v*)&svl[ln * 264 + kf * 32 + q * 8];
  for (int nt = 0; nt < 6; ++nt) {
    const int c = w * 96 + nt * 16 + ln;  // col 0..767
    const int dirI = (c >= 384) ? 1 : 0;
    const int g = c - dirI * 384;
    const float biasx = bihI[c] + (g < 256 ? bhhI[c] : 0.f);  // fold r,z
    f32x4 cacc = {0.f, 0.f, 0.f, 0.f};
    for (int kf = 0; kf < 8; ++kf) {
      s8v bfx = *(const s8v*)&wib[(size_t)c * 256 + kf * 32 + q * 8];
      cacc = mfma16(afx[kf], bfx, cacc);
    }
    if (q < 2) {                          // rows 0..7 are real sv rows
      for (int r = 0; r < 4; ++r) {
        const int m = q * 4 + r;
        xgi[((size_t)dirI * 2048 + s * B_ + b0 + m) * 384 + g] = cacc[r] + biasx;
      }
    }
  }
}

// ============================================================================
// K5: inter biGRU. Grid 8 = (dir, b-quad of 16). Depth-3 pipelined gate loads.
// ============================================================================
__global__ __launch_bounds__(512) void k_inter(
    const float* __restrict__ xgi,   // r,z biases folded
    const float* __restrict__ whh,   // [2][384][128] fp32
    const float* __restrict__ bhh,   // [2][384] fp32 (n-gate used)
    float* __restrict__ io2)         // [S*B][256] fp32
{
  const int bid = blockIdx.x;
  const int dir = bid >> 2, bq = bid & 3, bbase = bq * 16;
  const int tid = threadIdx.x;
  const int w = tid >> 6, l = tid & 63, q = l >> 4, ln = l & 15;
  const int gbase = w * 16, g0 = gbase + q * 4;
  __shared__ __align__(16) unsigned short hb[2][16 * 136];
  for (int i = tid; i < 2 * 16 * 136; i += 512) ((unsigned short*)hb)[i] = 0;
  s8v af[3][4];
  float hbn[4];
  const float* whd = whh + (size_t)dir * (384 * 128);
  const float* bhd = bhh + dir * 384;
  for (int g3 = 0; g3 < 3; ++g3) {
    const int R = g3 * 128 + gbase;
    for (int kf = 0; kf < 4; ++kf)
      af[g3][kf] = cvt8(&whd[(size_t)(R + ln) * 128 + kf * 32 + q * 8]);
  }
  for (int r = 0; r < 4; ++r) hbn[r] = bhd[256 + gbase + q * 4 + r];
  float h[4] = {0.f, 0.f, 0.f, 0.f};
  const int b = bbase + ln;
  __syncthreads();

  float4 Vr[4], Vz[4], Vn[4];
#define GLOAD_S(slot, st)                                                   \
  do {                                                                      \
    int tt_ = (st) > (S_ - 1) ? (S_ - 1) : (st);                            \
    int sg_ = dir ? (S_ - 1 - tt_) : tt_;                                   \
    const float* xp_ = xgi + ((size_t)dir * 2048 + sg_ * 64 + b) * 384 + g0;\
    Vr[slot] = *(const float4*)&xp_[0];                                     \
    Vz[slot] = *(const float4*)&xp_[128];                                   \
    Vn[slot] = *(const float4*)&xp_[256];                                   \
  } while (0)

  GLOAD_S(0, 0);
  GLOAD_S(1, 1);
  GLOAD_S(2, 2);

  int p = 0;
  for (int it = 0; it < S_ / 4; ++it) {
#pragma unroll
    for (int j = 0; j < 4; ++j) {
      const int step = it * 4 + j;
      const int sI = dir ? (S_ - 1 - step) : step;
      GLOAD_S((j + 3) & 3, step + 3);

      s8v bfr[4];
      for (int kf = 0; kf < 4; ++kf)
        bfr[kf] = *(const s8v*)&hb[p][ln * 136 + kf * 32 + q * 8];
      f32x4 c0 = {0.f, 0.f, 0.f, 0.f}, c1 = c0, c2 = c0;
      for (int kf = 0; kf < 4; ++kf) {
        c0 = mfma16(af[0][kf], bfr[kf], c0);
        c1 = mfma16(af[1][kf], bfr[kf], c1);
        c2 = mfma16(af[2][kf], bfr[kf], c2);
      }
      const float irv[4] = {Vr[j].x, Vr[j].y, Vr[j].z, Vr[j].w};
      const float izv[4] = {Vz[j].x, Vz[j].y, Vz[j].z, Vz[j].w};
      const float inv[4] = {Vn[j].x, Vn[j].y, Vn[j].z, Vn[j].w};
      unsigned short hnb[4];
      for (int r = 0; r < 4; ++r) {
        float rr = fsigm(irv[r] + c0[r]);
        float zz = fsigm(izv[r] + c1[r]);
        float nn = ftanh(inv[r] + rr * (c2[r] + hbn[r]));
        float hv = zz * (h[r] - nn) + nn;
        h[r] = hv;
        hnb[r] = f2b(hv);
      }
      ushort4 hv4; hv4.x = hnb[0]; hv4.y = hnb[1]; hv4.z = hnb[2]; hv4.w = hnb[3];
      *(ushort4*)&hb[p ^ 1][ln * 136 + g0] = hv4;
      float4 of4; of4.x = h[0]; of4.y = h[1]; of4.z = h[2]; of4.w = h[3];
      *(float4*)&io2[((size_t)(sI * 64 + b)) * 256 + dir * 128 + g0] = of4;
      lds_barrier();
      p ^= 1;
    }
  }
#undef GLOAD_S
}

// ============================================================================
// K6: a2[s*64+b] = proj_inter . tanh(io2 @ W_W_inter + b_inter)  (no softmax)
// ============================================================================
__global__ __launch_bounds__(256) void k_attn_i(
    const float* __restrict__ io2,
    const float* __restrict__ wwI,   // [256][256] fp32 h-major
    const float* __restrict__ bI,
    const float* __restrict__ projI,
    float* __restrict__ a2)          // [2048]
{
  const int bid = blockIdx.x, tid = threadIdx.x;
  const int r0 = bid * 8;
  __shared__ float iol[8 * 256];
  __shared__ float red[4 * 8];
  for (int i = 0; i < 8; ++i) iol[i * 256 + tid] = io2[(size_t)(r0 + i) * 256 + tid];
  __syncthreads();
  float acc[8];
  for (int i = 0; i < 8; ++i) acc[i] = 0.f;
  for (int hh = 0; hh < 256; ++hh) {
    const float wv = wwI[hh * 256 + tid];
    for (int i = 0; i < 8; ++i) acc[i] += wv * iol[i * 256 + hh];
  }
  const float bb = bI[tid], pp = projI[tid];
  float p[8];
  for (int i = 0; i < 8; ++i) p[i] = pp * ftanh(acc[i] + bb);
  for (int d = 1; d < 64; d <<= 1)
    for (int i = 0; i < 8; ++i) p[i] += __shfl_xor(p[i], d);
  const int w = tid >> 6, l = tid & 63;
  if (l == 0)
    for (int i = 0; i < 8; ++i) red[w * 8 + i] = p[i];
  __syncthreads();
  if (tid < 8) a2[r0 + tid] = red[tid] + red[8 + tid] + red[16 + tid] + red[24 + tid];
}

// ============================================================================
// K7: doc_vec = sum_s a2 * io2 ; out = doc @ W_final^T + b_final  (fp32 out)
// ============================================================================
__global__ __launch_bounds__(256) void k_final(
    const float* __restrict__ a2,
    const float* __restrict__ io2,
    const float* __restrict__ wf,    // [5][256] fp32
    const float* __restrict__ bfi,   // [5] fp32
    float* __restrict__ out)         // [64][5] fp32
{
  const int b = blockIdx.x, tid = threadIdx.x;
  __shared__ float av[S_];
  __shared__ float dv[256];
  __shared__ float red[4];
  if (tid < S_) av[tid] = a2[tid * 64 + b];
  __syncthreads();
  float acc = 0.f;
  for (int s = 0; s < S_; ++s) acc += av[s] * io2[((size_t)(s * 64 + b)) * 256 + tid];
  dv[tid] = acc;
  __syncthreads();
  for (int c = 0; c < C_; ++c) {
    float pv = wf[c * 256 + tid] * dv[tid];
    for (int d = 1; d < 64; d <<= 1) pv += __shfl_xor(pv, d);
    const int w = tid >> 6, l = tid & 63;
    if (l == 0) red[w] = pv;
    __syncthreads();
    if (tid == 0)
      out[b * C_ + c] = red[0] + red[1] + red[2] + red[3] + bfi[c];
    __syncthreads();
  }
}

// ============================================================================
extern "C" void kernel_launch(void* const* d_in, const int* in_sizes, int n_in,
                              void* d_out, int out_size, void* d_ws, size_t ws_size,
                              hipStream_t stream) {
  (void)in_sizes; (void)n_in; (void)out_size; (void)ws_size;
  const int*   tokens = (const int*)d_in[0];
  const float* emb    = (const float*)d_in[1];
  const float* wih_a  = (const float*)d_in[2];
  const float* whh_a  = (const float*)d_in[3];
  const float* bih_a  = (const float*)d_in[4];
  const float* bhh_a  = (const float*)d_in[5];
  const float* ww_a   = (const float*)d_in[6];
  const float* b_a    = (const float*)d_in[7];
  const float* proj_a = (const float*)d_in[8];
  const float* wih_i  = (const float*)d_in[9];
  const float* whh_i  = (const float*)d_in[10];
  const float* bih_i  = (const float*)d_in[11];
  const float* bhh_i  = (const float*)d_in[12];
  const float* ww_i   = (const float*)d_in[13];
  const float* b_i    = (const float*)d_in[14];
  const float* proj_i = (const float*)d_in[15];
  const float* w_fin  = (const float*)d_in[16];
  const float* b_fin  = (const float*)d_in[17];

  char* ws = (char*)d_ws;
  unsigned short* gtab = (unsigned short*)(ws + 0);          // 49,152,000 B
  unsigned short* wta  = (unsigned short*)(ws + 49152000);   //    131,072 B
  unsigned short* iout = (unsigned short*)(ws + 49283072);   // 67,108,864 B
  unsigned short* wib  = (unsigned short*)(ws + 116391936);  //    393,216 B
  float* xgi = (float*)(ws + 119537664);                     //  6,291,456 B
  float* io2 = (float*)(ws + 125829120);                     //  2,097,152 B
  float* a2  = (float*)(ws + 127926272);                     //      8,192 B

  k_gtab<<<508, 256, 0, stream>>>(emb, wih_a, bih_a, bhh_a, ww_a, wih_i,
                                  gtab, wta, wib);
  k_intra<<<256, 512, 0, stream>>>(tokens, gtab, whh_a, bhh_a, iout);
  k_attn<<<256, 512, 0, stream>>>(iout, wta, b_a, proj_a, wib, bih_i, bhh_i, xgi);
  k_inter<<<8, 512, 0, stream>>>(xgi, whh_i, bhh_i, io2);
  k_attn_i<<<256, 256, 0, stream>>>(io2, ww_i, b_i, proj_i, a2);
  k_final<<<64, 256, 0, stream>>>(a2, io2, w_fin, b_fin, (float*)d_out);
}